// Round 6
// baseline (432.202 us; speedup 1.0000x reference)
//
#include <hip/hip_runtime.h>
#include <math.h>

// ---------------------------------------------------------------------------
// VoxelMlp forward, round 6:
//  - ws_size-dependent prep: big path (G in ws, direct transpose, 5 dispatches)
//    vs fallback in-place path (r5 chain) if ws is small.
//  - fused kernel LDS diet 71.7->54.3 KB => 3 blocks/CU: h1 stored bf16-hi only
//    (weight residual kept in L2 MFMA), dec_w1 epilogue via uniform s_loads.
// ---------------------------------------------------------------------------

#define N_RAYS 4096
#define ACT_SHIFT_F (-4.595119850134589f)
#define LOG1EM10 (-23.025850929940457f)
#define GV 2097152            // 128^3
#define GVH 1048576           // 128^3 / 2

typedef __attribute__((ext_vector_type(8))) short bf16x8;
typedef __attribute__((ext_vector_type(4))) float f32x4;
#define MFMA16(a, b, c) __builtin_amdgcn_mfma_f32_16x16x32_bf16(a, b, c, 0, 0, 0)

__device__ __forceinline__ short bf16r(float f) {   // RNE f32 -> bf16
    unsigned int u = __float_as_uint(f);
    u += 0x7FFF + ((u >> 16) & 1);
    return (short)(u >> 16);
}
__device__ __forceinline__ float bf2f(unsigned short s) {
    return __uint_as_float(((unsigned int)s) << 16);
}

// accumulate w * (12 bf16 channels) from channel-last grid
__device__ __forceinline__ void acc12(const short* __restrict__ g, int vox, float w,
                                      float* __restrict__ feat) {
    const ushort4* qp = (const ushort4*)(g + (size_t)vox * 12);
    const ushort4 a = qp[0], b = qp[1], c = qp[2];
    feat[0] += w * bf2f(a.x); feat[1] += w * bf2f(a.y); feat[2]  += w * bf2f(a.z); feat[3]  += w * bf2f(a.w);
    feat[4] += w * bf2f(b.x); feat[5] += w * bf2f(b.y); feat[6]  += w * bf2f(b.z); feat[7]  += w * bf2f(b.w);
    feat[8] += w * bf2f(c.x); feat[9] += w * bf2f(c.y); feat[10] += w * bf2f(c.z); feat[11] += w * bf2f(c.w);
}

// ---------------------------------------------------------------------------
// pack weights (blocks 0..287) + timenet/bias-fold (block 288).
// pack: elem e = ((nt*KT+kt)*64+lane)*8+j holds W[kt*32+(lane>>4)*8+j][nt*16+(lane&15)]
// ---------------------------------------------------------------------------
__global__ __launch_bounds__(256) void pack_timenet_kernel(
    const float* __restrict__ dt_w0, const float* __restrict__ dt_w1,
    const float* __restrict__ fn_w0, const float* __restrict__ dec_wf,
    const float* __restrict__ dec_w0,
    const float* __restrict__ ft,
    const float* __restrict__ tw0, const float* __restrict__ tb0,
    const float* __restrict__ tw1, const float* __restrict__ tb1,
    const float* __restrict__ dt_b0,
    short* __restrict__ dt0h, short* __restrict__ dt0l,
    short* __restrict__ dt1h, short* __restrict__ dt1l,
    short* __restrict__ fnw, short* __restrict__ dwf, short* __restrict__ dw0,
    float* __restrict__ be0)
{
    const int tid = threadIdx.x;
    if (blockIdx.x == 288) {
        // timenet + fold tf into deform-L1 bias: be0 = dt_b0 + tf @ dt_w0[27:87]
        __shared__ float sh[128];
        __shared__ float stf[60];
        const float t = ft[0];
        float te[9];
        te[0] = t;
        float fr = 1.f;
#pragma unroll
        for (int f = 0; f < 4; f++) {
            te[1 + f] = __sinf(t * fr);
            te[5 + f] = __cosf(t * fr);
            fr *= 2.f;
        }
        if (tid < 128) {
            float acc = tb0[tid];
#pragma unroll
            for (int k = 0; k < 9; k++) acc = fmaf(te[k], tw0[k * 128 + tid], acc);
            sh[tid] = fmaxf(acc, 0.f);
        }
        __syncthreads();
        if (tid < 60) {
            float acc = tb1[tid];
            for (int k = 0; k < 128; k++) acc = fmaf(sh[k], tw1[k * 60 + tid], acc);
            stf[tid] = acc;
        }
        __syncthreads();
        if (tid < 128) {
            float acc = dt_b0[tid];
            for (int k = 0; k < 60; k++) acc = fmaf(stf[k], dt_w0[(27 + k) * 128 + tid], acc);
            be0[tid] = acc;
        }
        return;
    }
    const int id = blockIdx.x * 256 + tid;   // < 73728
    const float* W; short* dh; short* dl = nullptr; int In, KT, Out, e;
    if (id < 4096)       { W = dt_w0;  dh = dt0h; dl = dt0l; In = 27;  KT = 1; Out = 128; e = id; }
    else if (id < 20480) { W = dt_w1;  dh = dt1h; dl = dt1l; In = 128; KT = 4; Out = 128; e = id - 4096; }
    else if (id < 49152) { W = fn_w0;  dh = fnw;             In = 207; KT = 7; Out = 128; e = id - 20480; }
    else if (id < 65536) { W = dec_wf; dh = dwf;             In = 128; KT = 4; Out = 128; e = id - 49152; }
    else                 { W = dec_w0; dh = dw0;             In = 128; KT = 4; Out = 64;  e = id - 65536; }
    const int j = e & 7, lane = (e >> 3) & 63, rest = e >> 9;
    const int kt = rest % KT, nt = rest / KT;
    const int n = nt * 16 + (lane & 15);
    const int k = kt * 32 + (lane >> 4) * 8 + j;
    const float v = (k < In) ? W[k * Out + n] : 0.f;
    const short hi = bf16r(v);
    dh[e] = hi;
    if (dl) dl[e] = bf16r(v - bf2f((unsigned short)hi));
}

// ---------------------------------------------------------------------------
// BIG path: direct transpose feature [12][128^3] f32 -> G [128^3][12] bf16 in ws
// ---------------------------------------------------------------------------
__global__ __launch_bounds__(256) void transpose_big_kernel(
    const float* __restrict__ f, short* __restrict__ G)
{
    const int v = blockIdx.x * 256 + threadIdx.x;   // < GV
    unsigned int us[12];
#pragma unroll
    for (int c = 0; c < 12; c++) us[c] = (unsigned short)bf16r(f[(size_t)c * GV + v]);
    uint2* dst = (uint2*)(G + (size_t)v * 12);
    dst[0] = make_uint2(us[0] | (us[1] << 16), us[2]  | (us[3]  << 16));
    dst[1] = make_uint2(us[4] | (us[5] << 16), us[6]  | (us[7]  << 16));
    dst[2] = make_uint2(us[8] | (us[9] << 16), us[10] | (us[11] << 16));
}

// ---------------------------------------------------------------------------
// SMALL-ws fallback: bounce-compact + 2-pass in-place transpose (r5 scheme)
// ---------------------------------------------------------------------------
__global__ __launch_bounds__(256) void compact_kernel(
    const float* __restrict__ f, short* __restrict__ B1, short* __restrict__ B2)
{
    const int id = blockIdx.x * 256 + threadIdx.x;   // < 9437184
    if (id < 3 * GV) {
        B1[id] = bf16r(f[id]);
    } else {
        const int e = id - 3 * GV;
        const int c = e >> 20;
        const int v2 = e & (GVH - 1);
        B2[e] = bf16r(f[(size_t)(3 + c) * GV + GVH + v2]);
    }
}

__global__ __launch_bounds__(256) void transpose_kernel(
    const float* __restrict__ f, const short* __restrict__ B1,
    const short* __restrict__ B2, short* __restrict__ G, int pass)
{
    const int idx = blockIdx.x * 256 + threadIdx.x;  // < GVH
    const int v = pass * GVH + idx;
    unsigned int us[12];
#pragma unroll
    for (int c = 0; c < 3; c++) us[c] = (unsigned short)B1[c * GV + v];
    if (pass == 0) {
#pragma unroll
        for (int c = 3; c < 12; c++) us[c] = (unsigned short)bf16r(f[(size_t)c * GV + v]);
    } else {
#pragma unroll
        for (int c = 3; c < 6; c++) us[c] = (unsigned short)B2[(c - 3) * GVH + idx];
#pragma unroll
        for (int c = 6; c < 12; c++) us[c] = (unsigned short)bf16r(f[(size_t)c * GV + v]);
    }
    uint2* dst = (uint2*)(G + (size_t)v * 12);
    dst[0] = make_uint2(us[0] | (us[1] << 16), us[2]  | (us[3]  << 16));
    dst[1] = make_uint2(us[4] | (us[5] << 16), us[6]  | (us[7]  << 16));
    dst[2] = make_uint2(us[8] | (us[9] << 16), us[10] | (us[11] << 16));
}

// 2x avg-pool, channel-last bf16 -> bf16.  so = log2(n_out)
__global__ __launch_bounds__(256) void pool_kernel(
    const short* __restrict__ src, short* __restrict__ dst, int so)
{
    const int nout = 1 << so, nin = nout << 1;
    const int idx = blockIdx.x * 256 + threadIdx.x;
    const int z = idx & (nout - 1), y = (idx >> so) & (nout - 1), x = idx >> (2 * so);
    float acc[12];
#pragma unroll
    for (int c = 0; c < 12; c++) acc[c] = 0.f;
#pragma unroll
    for (int i = 0; i < 2; i++)
#pragma unroll
        for (int j = 0; j < 2; j++)
#pragma unroll
            for (int k = 0; k < 2; k++) {
                const int vox = ((2 * x + i) * nin + (2 * y + j)) * nin + (2 * z + k);
                acc12(src, vox, 1.f, acc);
            }
    unsigned int us[12];
#pragma unroll
    for (int c = 0; c < 12; c++) us[c] = (unsigned short)bf16r(acc[c] * 0.125f);
    uint2* ob = (uint2*)(dst + (size_t)idx * 12);
    ob[0] = make_uint2(us[0] | (us[1] << 16), us[2]  | (us[3]  << 16));
    ob[1] = make_uint2(us[4] | (us[5] << 16), us[6]  | (us[7]  << 16));
    ob[2] = make_uint2(us[8] | (us[9] << 16), us[10] | (us[11] << 16));
}

// ---------------------------------------------------------------------------
// fused: emb -> deform L1/L2 MFMA -> dx -> density+scan | gathers -> featurenet
// -> decoder MFMA -> composite.  Block = 1 ray, 256 thr, 3 blocks/CU (54.3 KB).
// ---------------------------------------------------------------------------
__global__ __launch_bounds__(256) void fused_kernel(
    const float* __restrict__ ray_pts, const float* __restrict__ viewdirs,
    const float* __restrict__ be0,
    const short* __restrict__ dt0h, const short* __restrict__ dt0l,
    const short* __restrict__ dt1h, const short* __restrict__ dt1l,
    const float* __restrict__ dt_b1,
    const float* __restrict__ dt_wo, const float* __restrict__ dt_bo,
    const float* __restrict__ density,
    const short* __restrict__ g0, const short* __restrict__ p2g, const short* __restrict__ p4g,
    const short* __restrict__ fnw, const float* __restrict__ fn_b0,
    const short* __restrict__ dwf, const float* __restrict__ dec_bf,
    const short* __restrict__ dw0, const float* __restrict__ dec_b0,
    const float* __restrict__ dec_w0, const float* __restrict__ dec_w1,
    const float* __restrict__ dec_b1,
    float* __restrict__ out)
{
    // sA: emb (stride 72 sh) -> h2 f32 (stride 132 f32) -> X (232 sh) -> fl (136 sh)
    // sB: h1 bf16-hi (stride 136 sh) -> hf (136 sh) -> h2dec (72 sh)
    __shared__ __align__(16) short sA[16896];   // 33792 B
    __shared__ __align__(16) short sB[8704];    // 17408 B
    __shared__ float sWo[387];                  // dt_wo + dt_bo
    __shared__ float sSm[256];                  // [p*4+d]: pts_d xyz, d=3: weight
    __shared__ float sBe3[64];                  // folded decoder-L0 bias
    __shared__ float sAiv[1];

    const int tid = threadIdx.x;
    const int r = blockIdx.x;
    const int p0g = r * 64;
    const int lane = tid & 63, wv = tid >> 6;
    const int l15 = lane & 15, q = lane >> 4;
    const int ntb = wv * 2;

    // ---- phase 0: preloads + folded decoder bias + deform embedding ----
    for (int i = tid; i < 384; i += 256) sWo[i] = dt_wo[i];
    if (tid < 3) sWo[384 + tid] = dt_bo[tid];
    if (tid < 64) {   // be3[n] = dec_b0[n] + vemb . dec_w0[128:149][n]
        const float v0 = viewdirs[r * 3], v1 = viewdirs[r * 3 + 1], v2 = viewdirs[r * 3 + 2];
        const float vv[3] = { v0, v1, v2 };
        float ve[21];
        ve[0] = v0; ve[1] = v1; ve[2] = v2;
#pragma unroll
        for (int d = 0; d < 3; d++) {
            float fq = 1.f;
#pragma unroll
            for (int f = 0; f < 3; f++) {
                ve[3 + d * 3 + f]  = __sinf(vv[d] * fq);
                ve[12 + d * 3 + f] = __cosf(vv[d] * fq);
                fq *= 2.f;
            }
        }
        float acc = dec_b0[tid];
#pragma unroll
        for (int k = 0; k < 21; k++) acc = fmaf(ve[k], dec_w0[(128 + k) * 64 + tid], acc);
        sBe3[tid] = acc;
    }
    {   // deform emb: thread (p=lane, grp=wv) -> cols wv*8..wv*8+7 (hi) / +32 (lo)
        const int p = lane;
        const int gp = p0g + p;
        const float pt[3] = { ray_pts[gp * 3], ray_pts[gp * 3 + 1], ray_pts[gp * 3 + 2] };
        float vals[8];
#pragma unroll
        for (int j = 0; j < 8; j++) {
            const int c = wv * 8 + j;
            float v;
            if (c < 3)       v = pt[c];
            else if (c < 15) { const int e = c - 3;  v = __sinf(pt[e >> 2] * (float)(1 << (e & 3))); }
            else if (c < 27) { const int e = c - 15; v = __cosf(pt[e >> 2] * (float)(1 << (e & 3))); }
            else             v = 0.f;
            vals[j] = v;
        }
        bf16x8 hi, lo;
#pragma unroll
        for (int j = 0; j < 8; j++) {
            const short h = bf16r(vals[j]);
            hi[j] = h;
            lo[j] = bf16r(vals[j] - bf2f((unsigned short)h));
        }
        *(bf16x8*)(sA + p * 72 + wv * 8) = hi;
        *(bf16x8*)(sA + p * 72 + 32 + wv * 8) = lo;
    }
    __syncthreads();

    // ---- phase 1: deform L1  K=32, wave covers nt {ntb,ntb+1}, 4 m-tiles ----
    {
        f32x4 acc[4][2];
#pragma unroll
        for (int mt = 0; mt < 4; mt++)
#pragma unroll
            for (int n2 = 0; n2 < 2; n2++) acc[mt][n2] = (f32x4){0.f, 0.f, 0.f, 0.f};
        bf16x8 bh[2], bl[2];
#pragma unroll
        for (int n2 = 0; n2 < 2; n2++) {
            bh[n2] = *(const bf16x8*)(dt0h + ((ntb + n2) * 64 + lane) * 8);
            bl[n2] = *(const bf16x8*)(dt0l + ((ntb + n2) * 64 + lane) * 8);
        }
#pragma unroll
        for (int mt = 0; mt < 4; mt++) {
            const bf16x8 ah = *(const bf16x8*)(sA + (mt * 16 + l15) * 72 + q * 8);
            const bf16x8 al = *(const bf16x8*)(sA + (mt * 16 + l15) * 72 + 32 + q * 8);
#pragma unroll
            for (int n2 = 0; n2 < 2; n2++) {
                acc[mt][n2] = MFMA16(ah, bh[n2], acc[mt][n2]);
                acc[mt][n2] = MFMA16(al, bh[n2], acc[mt][n2]);
                acc[mt][n2] = MFMA16(ah, bl[n2], acc[mt][n2]);
            }
        }
#pragma unroll
        for (int n2 = 0; n2 < 2; n2++) {
            const int n0 = (ntb + n2) * 16 + l15;
            const float bv = be0[n0];
#pragma unroll
            for (int mt = 0; mt < 4; mt++)
#pragma unroll
                for (int rg = 0; rg < 4; rg++)
                    sB[(mt * 16 + q * 4 + rg) * 136 + n0] =
                        bf16r(fmaxf(acc[mt][n2][rg] + bv, 0.f));
        }
    }
    __syncthreads();

    // ---- phase 2: deform L2  K=128 (4 kt), weight-residual split; f32 -> sA ----
    {
        f32x4 acc[4][2];
#pragma unroll
        for (int mt = 0; mt < 4; mt++)
#pragma unroll
            for (int n2 = 0; n2 < 2; n2++) acc[mt][n2] = (f32x4){0.f, 0.f, 0.f, 0.f};
#pragma unroll
        for (int kt = 0; kt < 4; kt++) {
            bf16x8 a[4];
#pragma unroll
            for (int mt = 0; mt < 4; mt++)
                a[mt] = *(const bf16x8*)(sB + (mt * 16 + l15) * 136 + (kt * 4 + q) * 8);
#pragma unroll
            for (int n2 = 0; n2 < 2; n2++) {
                const bf16x8 bh = *(const bf16x8*)(dt1h + (((ntb + n2) * 4 + kt) * 64 + lane) * 8);
                const bf16x8 bl = *(const bf16x8*)(dt1l + (((ntb + n2) * 4 + kt) * 64 + lane) * 8);
#pragma unroll
                for (int mt = 0; mt < 4; mt++) {
                    acc[mt][n2] = MFMA16(a[mt], bh, acc[mt][n2]);
                    acc[mt][n2] = MFMA16(a[mt], bl, acc[mt][n2]);
                }
            }
        }
        float* sF = (float*)sA;
#pragma unroll
        for (int n2 = 0; n2 < 2; n2++) {
            const int n0 = (ntb + n2) * 16 + l15;
            const float bv = dt_b1[n0];
#pragma unroll
            for (int mt = 0; mt < 4; mt++)
#pragma unroll
                for (int rg = 0; rg < 4; rg++)
                    sF[(mt * 16 + q * 4 + rg) * 132 + n0] = fmaxf(acc[mt][n2][rg] + bv, 0.f);
        }
    }
    __syncthreads();

    // ---- phase 3a: dx (192 threads: 64 pts x 3 dims) -> pts_d to sSm ----
    if (tid < 192) {
        const int p = tid & 63, d = tid >> 6;
        const float* sF = (const float*)sA;
        float a = sWo[384 + d];
        for (int k = 0; k < 128; k += 4) {
            const float4 h = *(const float4*)&sF[p * 132 + k];
            a += h.x * sWo[k * 3 + d] + h.y * sWo[(k + 1) * 3 + d]
               + h.z * sWo[(k + 2) * 3 + d] + h.w * sWo[(k + 3) * 3 + d];
        }
        sSm[p * 4 + d] = ray_pts[(p0g + p) * 3 + d] + a;
    }
    __syncthreads();

    // ---- phase 3b: wave0 = density+alpha+scan+pts-emb; waves1-3 = gathers ----
    {
        const int p = lane;
        const float pd[3] = { sSm[p * 4], sSm[p * 4 + 1], sSm[p * 4 + 2] };
        if (wv == 0) {
            int i0[3]; float fr[3];
#pragma unroll
            for (int d = 0; d < 3; d++) {
                float t = (pd[d] + 1.f) * 63.5f;
                t = fminf(fmaxf(t, 0.f), 127.f - 1e-4f);
                const int i = (int)t;
                i0[d] = i; fr[d] = t - (float)i;
            }
            float dens = 0.f;
#pragma unroll
            for (int dx = 0; dx < 2; dx++)
#pragma unroll
                for (int dy = 0; dy < 2; dy++) {
                    const float wxy = (dx ? fr[0] : 1.f - fr[0]) * (dy ? fr[1] : 1.f - fr[1]);
                    const float* b = &density[((i0[0] + dx) * 128 + i0[1] + dy) * 128 + i0[2]];
                    dens += wxy * ((1.f - fr[2]) * b[0] + fr[2] * b[1]);
                }
            const float xs = dens + ACT_SHIFT_F;
            const float sp = fmaxf(xs, 0.f) + log1pf(expf(-fabsf(xs)));
            const float alpha = -expm1f(-sp * 0.5f);
            const float lm = fmaxf(-sp * 0.5f, LOG1EM10);
            float v = lm;
#pragma unroll
            for (int d = 1; d < 64; d <<= 1) {
                const float o = __shfl_up(v, d);
                if (p >= d) v += o;
            }
            sSm[p * 4 + 3] = alpha * expf(v - lm);
            if (p == 63) sAiv[0] = expf(v);
            // pts_d embedding -> X cols 180..206, zero pad 207..223
            sA[p * 232 + 180] = bf16r(pd[0]);
            sA[p * 232 + 181] = bf16r(pd[1]);
            sA[p * 232 + 182] = bf16r(pd[2]);
#pragma unroll
            for (int d = 0; d < 3; d++) {
                float fq = 1.f;
#pragma unroll
                for (int f = 0; f < 4; f++) {
                    sA[p * 232 + 183 + d * 4 + f] = bf16r(__sinf(pd[d] * fq));
                    sA[p * 232 + 195 + d * 4 + f] = bf16r(__cosf(pd[d] * fq));
                    fq *= 2.f;
                }
            }
            sA[p * 232 + 207] = 0;
            const bf16x8 zv = { 0, 0, 0, 0, 0, 0, 0, 0 };
            *(bf16x8*)(sA + p * 232 + 208) = zv;
            *(bf16x8*)(sA + p * 232 + 216) = zv;
        } else {
            const int s = wv - 1;
            const int n = (s == 0) ? 128 : ((s == 1) ? 64 : 32);
            const short* g = (s == 0) ? g0 : ((s == 1) ? p2g : p4g);
            const float dim = (float)(n - 1);
            int i0[3]; float fr[3];
#pragma unroll
            for (int d = 0; d < 3; d++) {
                float t = (pd[d] + 1.f) * 0.5f * dim;
                t = fminf(fmaxf(t, 0.f), dim - 1e-4f);
                const int i = (int)t;
                i0[d] = i; fr[d] = t - (float)i;
            }
            float feat[12];
#pragma unroll
            for (int c = 0; c < 12; c++) feat[c] = 0.f;
#pragma unroll
            for (int dx = 0; dx < 2; dx++)
#pragma unroll
                for (int dy = 0; dy < 2; dy++)
#pragma unroll
                    for (int dz = 0; dz < 2; dz++) {
                        const float wc = (dx ? fr[0] : 1.f - fr[0]) *
                                         (dy ? fr[1] : 1.f - fr[1]) *
                                         (dz ? fr[2] : 1.f - fr[2]);
                        const int vox = ((i0[0] + dx) * n + i0[1] + dy) * n + i0[2] + dz;
                        acc12(g, vox, wc, feat);
                    }
#pragma unroll
            for (int c = 0; c < 12; c++) {
                const float v = feat[c];
                const int j = s * 12 + c;
                sA[p * 232 + j] = bf16r(v);
                const unsigned s1 = (unsigned short)bf16r(__sinf(v));
                const unsigned s2 = (unsigned short)bf16r(__sinf(2.f * v));
                const unsigned c1 = (unsigned short)bf16r(__cosf(v));
                const unsigned c2 = (unsigned short)bf16r(__cosf(2.f * v));
                *(unsigned*)(sA + p * 232 + 36 + 2 * j)  = s1 | (s2 << 16);
                *(unsigned*)(sA + p * 232 + 108 + 2 * j) = c1 | (c2 << 16);
            }
        }
    }
    __syncthreads();

    // ---- phase 4: featurenet  K=224 (7 kt), relu -> sB (stride 136) ----
    {
        f32x4 acc[4][2];
#pragma unroll
        for (int mt = 0; mt < 4; mt++)
#pragma unroll
            for (int n2 = 0; n2 < 2; n2++) acc[mt][n2] = (f32x4){0.f, 0.f, 0.f, 0.f};
#pragma unroll
        for (int kt = 0; kt < 7; kt++) {
            bf16x8 a[4];
#pragma unroll
            for (int mt = 0; mt < 4; mt++)
                a[mt] = *(const bf16x8*)(sA + (mt * 16 + l15) * 232 + (kt * 4 + q) * 8);
#pragma unroll
            for (int n2 = 0; n2 < 2; n2++) {
                const bf16x8 b = *(const bf16x8*)(fnw + (((ntb + n2) * 7 + kt) * 64 + lane) * 8);
#pragma unroll
                for (int mt = 0; mt < 4; mt++) acc[mt][n2] = MFMA16(a[mt], b, acc[mt][n2]);
            }
        }
#pragma unroll
        for (int n2 = 0; n2 < 2; n2++) {
            const int n0 = (ntb + n2) * 16 + l15;
            const float bv = fn_b0[n0];
#pragma unroll
            for (int mt = 0; mt < 4; mt++)
#pragma unroll
                for (int rg = 0; rg < 4; rg++)
                    sB[(mt * 16 + q * 4 + rg) * 136 + n0] = bf16r(fmaxf(acc[mt][n2][rg] + bv, 0.f));
        }
    }
    __syncthreads();

    // ---- phase 5: dec_wf  K=128 (4 kt), no relu -> sA (stride 136) ----
    {
        f32x4 acc[4][2];
#pragma unroll
        for (int mt = 0; mt < 4; mt++)
#pragma unroll
            for (int n2 = 0; n2 < 2; n2++) acc[mt][n2] = (f32x4){0.f, 0.f, 0.f, 0.f};
#pragma unroll
        for (int kt = 0; kt < 4; kt++) {
            bf16x8 a[4];
#pragma unroll
            for (int mt = 0; mt < 4; mt++)
                a[mt] = *(const bf16x8*)(sB + (mt * 16 + l15) * 136 + (kt * 4 + q) * 8);
#pragma unroll
            for (int n2 = 0; n2 < 2; n2++) {
                const bf16x8 b = *(const bf16x8*)(dwf + (((ntb + n2) * 4 + kt) * 64 + lane) * 8);
#pragma unroll
                for (int mt = 0; mt < 4; mt++) acc[mt][n2] = MFMA16(a[mt], b, acc[mt][n2]);
            }
        }
#pragma unroll
        for (int n2 = 0; n2 < 2; n2++) {
            const int n0 = (ntb + n2) * 16 + l15;
            const float bv = dec_bf[n0];
#pragma unroll
            for (int mt = 0; mt < 4; mt++)
#pragma unroll
                for (int rg = 0; rg < 4; rg++)
                    sA[(mt * 16 + q * 4 + rg) * 136 + n0] = bf16r(acc[mt][n2][rg] + bv);
        }
    }
    __syncthreads();

    // ---- phase 6: dec_w0  K=128 (vemb folded in sBe3), N=64 (1 nt/wave) ----
    {
        f32x4 acc[4];
#pragma unroll
        for (int mt = 0; mt < 4; mt++) acc[mt] = (f32x4){0.f, 0.f, 0.f, 0.f};
#pragma unroll
        for (int kt = 0; kt < 4; kt++) {
            bf16x8 a[4];
#pragma unroll
            for (int mt = 0; mt < 4; mt++)
                a[mt] = *(const bf16x8*)(sA + (mt * 16 + l15) * 136 + (kt * 4 + q) * 8);
            const bf16x8 b = *(const bf16x8*)(dw0 + ((wv * 4 + kt) * 64 + lane) * 8);
#pragma unroll
            for (int mt = 0; mt < 4; mt++) acc[mt] = MFMA16(a[mt], b, acc[mt]);
        }
        const int n0 = wv * 16 + l15;
        const float bv = sBe3[n0];
#pragma unroll
        for (int mt = 0; mt < 4; mt++)
#pragma unroll
            for (int rg = 0; rg < 4; rg++)
                sB[(mt * 16 + q * 4 + rg) * 72 + n0] = bf16r(fmaxf(acc[mt][rg] + bv, 0.f));
    }
    __syncthreads();

    // ---- phase 7: 64->3 (dec_w1 via uniform s_loads), sigmoid, reduce, store ----
    if (tid < 64) {
        const int p = tid;
        float a0 = dec_b1[0], a1 = dec_b1[1], a2 = dec_b1[2];
#pragma unroll
        for (int g = 0; g < 8; g++) {
            const bf16x8 h = *(const bf16x8*)(sB + p * 72 + g * 8);
#pragma unroll
            for (int j = 0; j < 8; j++) {
                const float f = bf2f((unsigned short)h[j]);
                const int k = g * 8 + j;
                a0 += f * dec_w1[k * 3];
                a1 += f * dec_w1[k * 3 + 1];
                a2 += f * dec_w1[k * 3 + 2];
            }
        }
        const float wgt = sSm[p * 4 + 3];
        float r0 = wgt / (1.f + expf(-a0));
        float r1 = wgt / (1.f + expf(-a1));
        float r2 = wgt / (1.f + expf(-a2));
#pragma unroll
        for (int off = 32; off >= 1; off >>= 1) {
            r0 += __shfl_down(r0, off);
            r1 += __shfl_down(r1, off);
            r2 += __shfl_down(r2, off);
        }
        if (p == 0) {
            const float av = sAiv[0];
            out[r * 3]     = r0 + av;
            out[r * 3 + 1] = r1 + av;
            out[r * 3 + 2] = r2 + av;
        }
    }
}

// ---------------------------------------------------------------------------
extern "C" void kernel_launch(void* const* d_in, const int* in_sizes, int n_in,
                              void* d_out, int out_size, void* d_ws, size_t ws_size,
                              hipStream_t stream)
{
    const float* ray_pts    = (const float*)d_in[0];
    const float* viewdirs   = (const float*)d_in[1];
    const float* frame_time = (const float*)d_in[2];
    float*       feature    = (float*)d_in[3];          // clobbered only in small-ws path
    const float* density    = (const float*)d_in[4];
    const float* tn_w0 = (const float*)d_in[5];  const float* tn_b0 = (const float*)d_in[6];
    const float* tn_w1 = (const float*)d_in[7];  const float* tn_b1 = (const float*)d_in[8];
    const float* dt_w0 = (const float*)d_in[9];  const float* dt_b0 = (const float*)d_in[10];
    const float* dt_w1 = (const float*)d_in[11]; const float* dt_b1 = (const float*)d_in[12];
    const float* dt_wo = (const float*)d_in[13]; const float* dt_bo = (const float*)d_in[14];
    const float* fn_w0 = (const float*)d_in[15]; const float* fn_b0 = (const float*)d_in[16];
    const float* dec_wf = (const float*)d_in[17]; const float* dec_bf = (const float*)d_in[18];
    const float* dec_w0 = (const float*)d_in[19]; const float* dec_b0 = (const float*)d_in[20];
    const float* dec_w1 = (const float*)d_in[21]; const float* dec_b1 = (const float*)d_in[22];
    (void)in_sizes; (void)n_in; (void)out_size;

    char* ws = (char*)d_ws;
    const bool big = ws_size >= (size_t)57598464;

    short *G, *p2, *p4, *B1 = nullptr, *B2 = nullptr;
    float* be0; short *dt0h, *dt0l, *dt1h, *dt1l, *fnw, *dwf, *dw0;

    if (big) {
        G    = (short*)(ws + 0);            // 128^3*12 bf16 = 50331648 B
        p2   = (short*)(ws + 50331648);     // 64^3*12 bf16
        p4   = (short*)(ws + 56623104);     // 32^3*12 bf16
        be0  = (float*)(ws + 57409536);     // 128 f32
        dt0h = (short*)(ws + 57410048);
        dt0l = (short*)(ws + 57418240);
        dt1h = (short*)(ws + 57426432);
        dt1l = (short*)(ws + 57459200);
        fnw  = (short*)(ws + 57491968);
        dwf  = (short*)(ws + 57549312);
        dw0  = (short*)(ws + 57582080);     // ends 57598464
    } else {
        G    = (short*)feature;             // in-place in feature buffer
        B1   = (short*)(ws + 0);            // 3*GV bf16
        B2   = (short*)(ws + 12582912);     // 3*GVH bf16
        p2   = (short*)(ws + 0);            // reuse after transpose
        p4   = (short*)(ws + 6291456);
        be0  = (float*)(ws + 18874368);
        dt0h = (short*)(ws + 18874880);
        dt0l = (short*)(ws + 18883072);
        dt1h = (short*)(ws + 18891264);
        dt1l = (short*)(ws + 18924032);
        fnw  = (short*)(ws + 18956800);
        dwf  = (short*)(ws + 19014144);
        dw0  = (short*)(ws + 19046912);     // ends 19063296
    }

    pack_timenet_kernel<<<289, 256, 0, stream>>>(
        dt_w0, dt_w1, fn_w0, dec_wf, dec_w0,
        frame_time, tn_w0, tn_b0, tn_w1, tn_b1, dt_b0,
        dt0h, dt0l, dt1h, dt1l, fnw, dwf, dw0, be0);

    if (big) {
        transpose_big_kernel<<<8192, 256, 0, stream>>>(feature, G);
    } else {
        compact_kernel<<<36864, 256, 0, stream>>>(feature, B1, B2);
        transpose_kernel<<<4096, 256, 0, stream>>>(feature, B1, B2, G, 0);
        transpose_kernel<<<4096, 256, 0, stream>>>(feature, B1, B2, G, 1);
    }
    pool_kernel<<<1024, 256, 0, stream>>>(G, p2, 6);
    pool_kernel<<<128, 256, 0, stream>>>(p2, p4, 5);

    fused_kernel<<<4096, 256, 0, stream>>>(ray_pts, viewdirs, be0,
                                           dt0h, dt0l, dt1h, dt1l, dt_b1,
                                           dt_wo, dt_bo, density,
                                           G, p2, p4,
                                           fnw, fn_b0, dwf, dec_bf,
                                           dw0, dec_b0, dec_w0, dec_w1, dec_b1,
                                           (float*)d_out);
}

// Round 7
// 414.485 us; speedup vs baseline: 1.0427x; 1.0427x over previous
//
#include <hip/hip_runtime.h>
#include <math.h>

// ---------------------------------------------------------------------------
// VoxelMlp forward, round 7:
//  - prep chain vectorized 4 voxels/thread (float4 loads, uint4 stores):
//    compact/transpose/pool were 1-elem/thread scalar => ~1 TB/s; now 16B/lane.
//  - fused: dec_w1 restaged into LDS (dead sB space, loaded in phase 6) to fix
//    the r6 phase-7 s_load tail regression; sB stride 136->132.
// ---------------------------------------------------------------------------

#define N_RAYS 4096
#define ACT_SHIFT_F (-4.595119850134589f)
#define LOG1EM10 (-23.025850929940457f)
#define GV 2097152            // 128^3
#define GVH 1048576           // 128^3 / 2

typedef __attribute__((ext_vector_type(8))) short bf16x8;
typedef __attribute__((ext_vector_type(4))) float f32x4;
#define MFMA16(a, b, c) __builtin_amdgcn_mfma_f32_16x16x32_bf16(a, b, c, 0, 0, 0)

__device__ __forceinline__ short bf16r(float f) {   // RNE f32 -> bf16
    unsigned int u = __float_as_uint(f);
    u += 0x7FFF + ((u >> 16) & 1);
    return (short)(u >> 16);
}
__device__ __forceinline__ float bf2f(unsigned short s) {
    return __uint_as_float(((unsigned int)s) << 16);
}
__device__ __forceinline__ uint2 pack4(float4 x) {
    const unsigned a = (unsigned short)bf16r(x.x), b = (unsigned short)bf16r(x.y);
    const unsigned c = (unsigned short)bf16r(x.z), d = (unsigned short)bf16r(x.w);
    return make_uint2(a | (b << 16), c | (d << 16));
}

// store 4 voxels x 12 bf16 channels (96 B) as 6 uint4
__device__ __forceinline__ void store_vox4(short* __restrict__ dst,
                                           const unsigned short us[4][12]) {
    unsigned w[24];
#pragma unroll
    for (int j = 0; j < 24; j++) {
        const int a = (2 * j) / 12, ca = (2 * j) % 12;
        const int b = (2 * j + 1) / 12, cb = (2 * j + 1) % 12;
        w[j] = (unsigned)us[a][ca] | ((unsigned)us[b][cb] << 16);
    }
    uint4* o = (uint4*)dst;
#pragma unroll
    for (int t = 0; t < 6; t++)
        o[t] = make_uint4(w[4 * t], w[4 * t + 1], w[4 * t + 2], w[4 * t + 3]);
}

// accumulate w * (12 bf16 channels) from channel-last grid
__device__ __forceinline__ void acc12(const short* __restrict__ g, int vox, float w,
                                      float* __restrict__ feat) {
    const ushort4* qp = (const ushort4*)(g + (size_t)vox * 12);
    const ushort4 a = qp[0], b = qp[1], c = qp[2];
    feat[0] += w * bf2f(a.x); feat[1] += w * bf2f(a.y); feat[2]  += w * bf2f(a.z); feat[3]  += w * bf2f(a.w);
    feat[4] += w * bf2f(b.x); feat[5] += w * bf2f(b.y); feat[6]  += w * bf2f(b.z); feat[7]  += w * bf2f(b.w);
    feat[8] += w * bf2f(c.x); feat[9] += w * bf2f(c.y); feat[10] += w * bf2f(c.z); feat[11] += w * bf2f(c.w);
}

// ---------------------------------------------------------------------------
// pack weights (blocks 0..287) + timenet/bias-fold (block 288).
// ---------------------------------------------------------------------------
__global__ __launch_bounds__(256) void pack_timenet_kernel(
    const float* __restrict__ dt_w0, const float* __restrict__ dt_w1,
    const float* __restrict__ fn_w0, const float* __restrict__ dec_wf,
    const float* __restrict__ dec_w0,
    const float* __restrict__ ft,
    const float* __restrict__ tw0, const float* __restrict__ tb0,
    const float* __restrict__ tw1, const float* __restrict__ tb1,
    const float* __restrict__ dt_b0,
    short* __restrict__ dt0h, short* __restrict__ dt0l,
    short* __restrict__ dt1h, short* __restrict__ dt1l,
    short* __restrict__ fnw, short* __restrict__ dwf, short* __restrict__ dw0,
    float* __restrict__ be0)
{
    const int tid = threadIdx.x;
    if (blockIdx.x == 288) {
        __shared__ float sh[128];
        __shared__ float stf[60];
        const float t = ft[0];
        float te[9];
        te[0] = t;
        float fr = 1.f;
#pragma unroll
        for (int f = 0; f < 4; f++) {
            te[1 + f] = __sinf(t * fr);
            te[5 + f] = __cosf(t * fr);
            fr *= 2.f;
        }
        if (tid < 128) {
            float acc = tb0[tid];
#pragma unroll
            for (int k = 0; k < 9; k++) acc = fmaf(te[k], tw0[k * 128 + tid], acc);
            sh[tid] = fmaxf(acc, 0.f);
        }
        __syncthreads();
        if (tid < 60) {
            float acc = tb1[tid];
            for (int k = 0; k < 128; k++) acc = fmaf(sh[k], tw1[k * 60 + tid], acc);
            stf[tid] = acc;
        }
        __syncthreads();
        if (tid < 128) {
            float acc = dt_b0[tid];
            for (int k = 0; k < 60; k++) acc = fmaf(stf[k], dt_w0[(27 + k) * 128 + tid], acc);
            be0[tid] = acc;
        }
        return;
    }
    const int id = blockIdx.x * 256 + tid;   // < 73728
    const float* W; short* dh; short* dl = nullptr; int In, KT, Out, e;
    if (id < 4096)       { W = dt_w0;  dh = dt0h; dl = dt0l; In = 27;  KT = 1; Out = 128; e = id; }
    else if (id < 20480) { W = dt_w1;  dh = dt1h; dl = dt1l; In = 128; KT = 4; Out = 128; e = id - 4096; }
    else if (id < 49152) { W = fn_w0;  dh = fnw;             In = 207; KT = 7; Out = 128; e = id - 20480; }
    else if (id < 65536) { W = dec_wf; dh = dwf;             In = 128; KT = 4; Out = 128; e = id - 49152; }
    else                 { W = dec_w0; dh = dw0;             In = 128; KT = 4; Out = 64;  e = id - 65536; }
    const int j = e & 7, lane = (e >> 3) & 63, rest = e >> 9;
    const int kt = rest % KT, nt = rest / KT;
    const int n = nt * 16 + (lane & 15);
    const int k = kt * 32 + (lane >> 4) * 8 + j;
    const float v = (k < In) ? W[k * Out + n] : 0.f;
    const short hi = bf16r(v);
    dh[e] = hi;
    if (dl) dl[e] = bf16r(v - bf2f((unsigned short)hi));
}

// ---------------------------------------------------------------------------
// BIG path: direct transpose, 4 voxels/thread
// ---------------------------------------------------------------------------
__global__ __launch_bounds__(256) void transpose_big_kernel(
    const float* __restrict__ f, short* __restrict__ G)
{
    const int v = (blockIdx.x * 256 + threadIdx.x) * 4;   // < GV
    unsigned short us[4][12];
#pragma unroll
    for (int c = 0; c < 12; c++) {
        const float4 x = *(const float4*)(f + (size_t)c * GV + v);
        us[0][c] = (unsigned short)bf16r(x.x);
        us[1][c] = (unsigned short)bf16r(x.y);
        us[2][c] = (unsigned short)bf16r(x.z);
        us[3][c] = (unsigned short)bf16r(x.w);
    }
    store_vox4(G + (size_t)v * 12, us);
}

// ---------------------------------------------------------------------------
// SMALL-ws: bounce-compact (4 elems/thread) + 2-pass in-place transpose (4/thr)
// ---------------------------------------------------------------------------
__global__ __launch_bounds__(256) void compact_kernel(
    const float* __restrict__ f, short* __restrict__ B1, short* __restrict__ B2)
{
    const int id = (blockIdx.x * 256 + threadIdx.x) * 4;   // < 9437184
    if (id < 3 * GV) {
        *(uint2*)(B1 + id) = pack4(*(const float4*)(f + id));
    } else {
        const int e = id - 3 * GV;
        const int c = e >> 20;
        const int v2 = e & (GVH - 1);
        *(uint2*)(B2 + e) = pack4(*(const float4*)(f + (size_t)(3 + c) * GV + GVH + v2));
    }
}

__global__ __launch_bounds__(256) void transpose_kernel(
    const float* __restrict__ f, const short* __restrict__ B1,
    const short* __restrict__ B2, short* __restrict__ G, int pass)
{
    const int idx = (blockIdx.x * 256 + threadIdx.x) * 4;  // < GVH
    const int v = pass * GVH + idx;
    unsigned short us[4][12];
#pragma unroll
    for (int c = 0; c < 3; c++) {
        const uint2 b = *(const uint2*)(B1 + c * GV + v);
        us[0][c] = (unsigned short)(b.x & 0xFFFF); us[1][c] = (unsigned short)(b.x >> 16);
        us[2][c] = (unsigned short)(b.y & 0xFFFF); us[3][c] = (unsigned short)(b.y >> 16);
    }
    if (pass == 0) {
#pragma unroll
        for (int c = 3; c < 12; c++) {
            const float4 x = *(const float4*)(f + (size_t)c * GV + v);
            us[0][c] = (unsigned short)bf16r(x.x);
            us[1][c] = (unsigned short)bf16r(x.y);
            us[2][c] = (unsigned short)bf16r(x.z);
            us[3][c] = (unsigned short)bf16r(x.w);
        }
    } else {
#pragma unroll
        for (int c = 3; c < 6; c++) {
            const uint2 b = *(const uint2*)(B2 + (c - 3) * GVH + idx);
            us[0][c] = (unsigned short)(b.x & 0xFFFF); us[1][c] = (unsigned short)(b.x >> 16);
            us[2][c] = (unsigned short)(b.y & 0xFFFF); us[3][c] = (unsigned short)(b.y >> 16);
        }
#pragma unroll
        for (int c = 6; c < 12; c++) {
            const float4 x = *(const float4*)(f + (size_t)c * GV + v);
            us[0][c] = (unsigned short)bf16r(x.x);
            us[1][c] = (unsigned short)bf16r(x.y);
            us[2][c] = (unsigned short)bf16r(x.z);
            us[3][c] = (unsigned short)bf16r(x.w);
        }
    }
    store_vox4(G + (size_t)v * 12, us);
}

// 2x avg-pool, channel-last bf16 -> bf16, 4 output voxels (consecutive z)/thread
__global__ __launch_bounds__(256) void pool_kernel(
    const short* __restrict__ src, short* __restrict__ dst, int so)
{
    const int nout = 1 << so, nin = nout << 1;
    const int idx = (blockIdx.x * 256 + threadIdx.x) * 4;
    const int z0 = idx & (nout - 1), y = (idx >> so) & (nout - 1), x = idx >> (2 * so);
    float acc[4][12];
#pragma unroll
    for (int k = 0; k < 4; k++)
#pragma unroll
        for (int c = 0; c < 12; c++) acc[k][c] = 0.f;
#pragma unroll
    for (int i = 0; i < 2; i++)
#pragma unroll
        for (int j = 0; j < 2; j++) {
            const size_t roff = (size_t)(((2 * x + i) * nin + (2 * y + j)) * nin + 2 * z0) * 12;
            const uint4* R4 = (const uint4*)(src + roff);
            uint4 U[12];
#pragma unroll
            for (int t = 0; t < 12; t++) U[t] = R4[t];
            const unsigned* W = (const unsigned*)U;   // 48 uints = 96 shorts
#pragma unroll
            for (int k = 0; k < 4; k++)
#pragma unroll
                for (int c = 0; c < 12; c++) {
                    const int s0 = 24 * k + c, s1 = 24 * k + 12 + c;
                    const unsigned u0 = W[s0 >> 1], u1 = W[s1 >> 1];
                    acc[k][c] += bf2f((unsigned short)((s0 & 1) ? (u0 >> 16) : (u0 & 0xFFFF)))
                               + bf2f((unsigned short)((s1 & 1) ? (u1 >> 16) : (u1 & 0xFFFF)));
                }
        }
    unsigned short us[4][12];
#pragma unroll
    for (int k = 0; k < 4; k++)
#pragma unroll
        for (int c = 0; c < 12; c++) us[k][c] = (unsigned short)bf16r(acc[k][c] * 0.125f);
    store_vox4(dst + (size_t)idx * 12, us);
}

// ---------------------------------------------------------------------------
// fused: emb -> deform L1/L2 MFMA -> dx -> density+scan | gathers -> featurenet
// -> decoder MFMA -> composite.  Block = 1 ray, 256 thr, LDS 53520 B.
// ---------------------------------------------------------------------------
__global__ __launch_bounds__(256) void fused_kernel(
    const float* __restrict__ ray_pts, const float* __restrict__ viewdirs,
    const float* __restrict__ be0,
    const short* __restrict__ dt0h, const short* __restrict__ dt0l,
    const short* __restrict__ dt1h, const short* __restrict__ dt1l,
    const float* __restrict__ dt_b1,
    const float* __restrict__ dt_wo, const float* __restrict__ dt_bo,
    const float* __restrict__ density,
    const short* __restrict__ g0, const short* __restrict__ p2g, const short* __restrict__ p4g,
    const short* __restrict__ fnw, const float* __restrict__ fn_b0,
    const short* __restrict__ dwf, const float* __restrict__ dec_bf,
    const short* __restrict__ dw0, const float* __restrict__ dec_b0,
    const float* __restrict__ dec_w0, const float* __restrict__ dec_w1,
    const float* __restrict__ dec_b1,
    float* __restrict__ out)
{
    // sA: emb (stride 72) -> h2 f32 (stride 132 f32) -> X (232) -> fl (136)
    // sB: h1 (stride 132) -> hf (stride 132) -> h2dec (stride 72) + sDw stage
    __shared__ __align__(16) short sA[16896];   // 33792 B
    __shared__ __align__(16) short sB[8448];    // 16896 B
    __shared__ float sWo[387];                  // dt_wo + dt_bo
    __shared__ float sSm[256];                  // [p*4+d]: pts_d xyz, d=3: weight
    __shared__ float sBe3[64];                  // folded decoder-L0 bias
    __shared__ float sAiv[1];

    const int tid = threadIdx.x;
    const int r = blockIdx.x;
    const int p0g = r * 64;
    const int lane = tid & 63, wv = tid >> 6;
    const int l15 = lane & 15, q = lane >> 4;
    const int ntb = wv * 2;

    // ---- phase 0: preloads + folded decoder bias + deform embedding ----
    for (int i = tid; i < 384; i += 256) sWo[i] = dt_wo[i];
    if (tid < 3) sWo[384 + tid] = dt_bo[tid];
    if (tid < 64) {   // be3[n] = dec_b0[n] + vemb . dec_w0[128:149][n]
        const float v0 = viewdirs[r * 3], v1 = viewdirs[r * 3 + 1], v2 = viewdirs[r * 3 + 2];
        const float vv[3] = { v0, v1, v2 };
        float ve[21];
        ve[0] = v0; ve[1] = v1; ve[2] = v2;
#pragma unroll
        for (int d = 0; d < 3; d++) {
            float fq = 1.f;
#pragma unroll
            for (int f = 0; f < 3; f++) {
                ve[3 + d * 3 + f]  = __sinf(vv[d] * fq);
                ve[12 + d * 3 + f] = __cosf(vv[d] * fq);
                fq *= 2.f;
            }
        }
        float acc = dec_b0[tid];
#pragma unroll
        for (int k = 0; k < 21; k++) acc = fmaf(ve[k], dec_w0[(128 + k) * 64 + tid], acc);
        sBe3[tid] = acc;
    }
    {   // deform emb: thread (p=lane, grp=wv) -> cols wv*8..wv*8+7 (hi) / +32 (lo)
        const int p = lane;
        const int gp = p0g + p;
        const float pt[3] = { ray_pts[gp * 3], ray_pts[gp * 3 + 1], ray_pts[gp * 3 + 2] };
        float vals[8];
#pragma unroll
        for (int j = 0; j < 8; j++) {
            const int c = wv * 8 + j;
            float v;
            if (c < 3)       v = pt[c];
            else if (c < 15) { const int e = c - 3;  v = __sinf(pt[e >> 2] * (float)(1 << (e & 3))); }
            else if (c < 27) { const int e = c - 15; v = __cosf(pt[e >> 2] * (float)(1 << (e & 3))); }
            else             v = 0.f;
            vals[j] = v;
        }
        bf16x8 hi, lo;
#pragma unroll
        for (int j = 0; j < 8; j++) {
            const short h = bf16r(vals[j]);
            hi[j] = h;
            lo[j] = bf16r(vals[j] - bf2f((unsigned short)h));
        }
        *(bf16x8*)(sA + p * 72 + wv * 8) = hi;
        *(bf16x8*)(sA + p * 72 + 32 + wv * 8) = lo;
    }
    __syncthreads();

    // ---- phase 1: deform L1  K=32, wave covers nt {ntb,ntb+1}, 4 m-tiles ----
    {
        f32x4 acc[4][2];
#pragma unroll
        for (int mt = 0; mt < 4; mt++)
#pragma unroll
            for (int n2 = 0; n2 < 2; n2++) acc[mt][n2] = (f32x4){0.f, 0.f, 0.f, 0.f};
        bf16x8 bh[2], bl[2];
#pragma unroll
        for (int n2 = 0; n2 < 2; n2++) {
            bh[n2] = *(const bf16x8*)(dt0h + ((ntb + n2) * 64 + lane) * 8);
            bl[n2] = *(const bf16x8*)(dt0l + ((ntb + n2) * 64 + lane) * 8);
        }
#pragma unroll
        for (int mt = 0; mt < 4; mt++) {
            const bf16x8 ah = *(const bf16x8*)(sA + (mt * 16 + l15) * 72 + q * 8);
            const bf16x8 al = *(const bf16x8*)(sA + (mt * 16 + l15) * 72 + 32 + q * 8);
#pragma unroll
            for (int n2 = 0; n2 < 2; n2++) {
                acc[mt][n2] = MFMA16(ah, bh[n2], acc[mt][n2]);
                acc[mt][n2] = MFMA16(al, bh[n2], acc[mt][n2]);
                acc[mt][n2] = MFMA16(ah, bl[n2], acc[mt][n2]);
            }
        }
#pragma unroll
        for (int n2 = 0; n2 < 2; n2++) {
            const int n0 = (ntb + n2) * 16 + l15;
            const float bv = be0[n0];
#pragma unroll
            for (int mt = 0; mt < 4; mt++)
#pragma unroll
                for (int rg = 0; rg < 4; rg++)
                    sB[(mt * 16 + q * 4 + rg) * 132 + n0] =
                        bf16r(fmaxf(acc[mt][n2][rg] + bv, 0.f));
        }
    }
    __syncthreads();

    // ---- phase 2: deform L2  K=128 (4 kt), weight-residual split; f32 -> sA ----
    {
        f32x4 acc[4][2];
#pragma unroll
        for (int mt = 0; mt < 4; mt++)
#pragma unroll
            for (int n2 = 0; n2 < 2; n2++) acc[mt][n2] = (f32x4){0.f, 0.f, 0.f, 0.f};
#pragma unroll
        for (int kt = 0; kt < 4; kt++) {
            bf16x8 a[4];
#pragma unroll
            for (int mt = 0; mt < 4; mt++)
                a[mt] = *(const bf16x8*)(sB + (mt * 16 + l15) * 132 + (kt * 4 + q) * 8);
#pragma unroll
            for (int n2 = 0; n2 < 2; n2++) {
                const bf16x8 bh = *(const bf16x8*)(dt1h + (((ntb + n2) * 4 + kt) * 64 + lane) * 8);
                const bf16x8 bl = *(const bf16x8*)(dt1l + (((ntb + n2) * 4 + kt) * 64 + lane) * 8);
#pragma unroll
                for (int mt = 0; mt < 4; mt++) {
                    acc[mt][n2] = MFMA16(a[mt], bh, acc[mt][n2]);
                    acc[mt][n2] = MFMA16(a[mt], bl, acc[mt][n2]);
                }
            }
        }
        float* sF = (float*)sA;
#pragma unroll
        for (int n2 = 0; n2 < 2; n2++) {
            const int n0 = (ntb + n2) * 16 + l15;
            const float bv = dt_b1[n0];
#pragma unroll
            for (int mt = 0; mt < 4; mt++)
#pragma unroll
                for (int rg = 0; rg < 4; rg++)
                    sF[(mt * 16 + q * 4 + rg) * 132 + n0] = fmaxf(acc[mt][n2][rg] + bv, 0.f);
        }
    }
    __syncthreads();

    // ---- phase 3a: dx (192 threads: 64 pts x 3 dims) -> pts_d to sSm ----
    if (tid < 192) {
        const int p = tid & 63, d = tid >> 6;
        const float* sF = (const float*)sA;
        float a = sWo[384 + d];
        for (int k = 0; k < 128; k += 4) {
            const float4 h = *(const float4*)&sF[p * 132 + k];
            a += h.x * sWo[k * 3 + d] + h.y * sWo[(k + 1) * 3 + d]
               + h.z * sWo[(k + 2) * 3 + d] + h.w * sWo[(k + 3) * 3 + d];
        }
        sSm[p * 4 + d] = ray_pts[(p0g + p) * 3 + d] + a;
    }
    __syncthreads();

    // ---- phase 3b: wave0 = density+alpha+scan+pts-emb; waves1-3 = gathers ----
    {
        const int p = lane;
        const float pd[3] = { sSm[p * 4], sSm[p * 4 + 1], sSm[p * 4 + 2] };
        if (wv == 0) {
            int i0[3]; float fr[3];
#pragma unroll
            for (int d = 0; d < 3; d++) {
                float t = (pd[d] + 1.f) * 63.5f;
                t = fminf(fmaxf(t, 0.f), 127.f - 1e-4f);
                const int i = (int)t;
                i0[d] = i; fr[d] = t - (float)i;
            }
            float dens = 0.f;
#pragma unroll
            for (int dx = 0; dx < 2; dx++)
#pragma unroll
                for (int dy = 0; dy < 2; dy++) {
                    const float wxy = (dx ? fr[0] : 1.f - fr[0]) * (dy ? fr[1] : 1.f - fr[1]);
                    const float* b = &density[((i0[0] + dx) * 128 + i0[1] + dy) * 128 + i0[2]];
                    dens += wxy * ((1.f - fr[2]) * b[0] + fr[2] * b[1]);
                }
            const float xs = dens + ACT_SHIFT_F;
            const float sp = fmaxf(xs, 0.f) + log1pf(expf(-fabsf(xs)));
            const float alpha = -expm1f(-sp * 0.5f);
            const float lm = fmaxf(-sp * 0.5f, LOG1EM10);
            float v = lm;
#pragma unroll
            for (int d = 1; d < 64; d <<= 1) {
                const float o = __shfl_up(v, d);
                if (p >= d) v += o;
            }
            sSm[p * 4 + 3] = alpha * expf(v - lm);
            if (p == 63) sAiv[0] = expf(v);
            // pts_d embedding -> X cols 180..206, zero pad 207..223
            sA[p * 232 + 180] = bf16r(pd[0]);
            sA[p * 232 + 181] = bf16r(pd[1]);
            sA[p * 232 + 182] = bf16r(pd[2]);
#pragma unroll
            for (int d = 0; d < 3; d++) {
                float fq = 1.f;
#pragma unroll
                for (int f = 0; f < 4; f++) {
                    sA[p * 232 + 183 + d * 4 + f] = bf16r(__sinf(pd[d] * fq));
                    sA[p * 232 + 195 + d * 4 + f] = bf16r(__cosf(pd[d] * fq));
                    fq *= 2.f;
                }
            }
            sA[p * 232 + 207] = 0;
            const bf16x8 zv = { 0, 0, 0, 0, 0, 0, 0, 0 };
            *(bf16x8*)(sA + p * 232 + 208) = zv;
            *(bf16x8*)(sA + p * 232 + 216) = zv;
        } else {
            const int s = wv - 1;
            const int n = (s == 0) ? 128 : ((s == 1) ? 64 : 32);
            const short* g = (s == 0) ? g0 : ((s == 1) ? p2g : p4g);
            const float dim = (float)(n - 1);
            int i0[3]; float fr[3];
#pragma unroll
            for (int d = 0; d < 3; d++) {
                float t = (pd[d] + 1.f) * 0.5f * dim;
                t = fminf(fmaxf(t, 0.f), dim - 1e-4f);
                const int i = (int)t;
                i0[d] = i; fr[d] = t - (float)i;
            }
            float feat[12];
#pragma unroll
            for (int c = 0; c < 12; c++) feat[c] = 0.f;
#pragma unroll
            for (int dx = 0; dx < 2; dx++)
#pragma unroll
                for (int dy = 0; dy < 2; dy++)
#pragma unroll
                    for (int dz = 0; dz < 2; dz++) {
                        const float wc = (dx ? fr[0] : 1.f - fr[0]) *
                                         (dy ? fr[1] : 1.f - fr[1]) *
                                         (dz ? fr[2] : 1.f - fr[2]);
                        const int vox = ((i0[0] + dx) * n + i0[1] + dy) * n + i0[2] + dz;
                        acc12(g, vox, wc, feat);
                    }
#pragma unroll
            for (int c = 0; c < 12; c++) {
                const float v = feat[c];
                const int j = s * 12 + c;
                sA[p * 232 + j] = bf16r(v);
                const unsigned s1 = (unsigned short)bf16r(__sinf(v));
                const unsigned s2 = (unsigned short)bf16r(__sinf(2.f * v));
                const unsigned c1 = (unsigned short)bf16r(__cosf(v));
                const unsigned c2 = (unsigned short)bf16r(__cosf(2.f * v));
                *(unsigned*)(sA + p * 232 + 36 + 2 * j)  = s1 | (s2 << 16);
                *(unsigned*)(sA + p * 232 + 108 + 2 * j) = c1 | (c2 << 16);
            }
        }
    }
    __syncthreads();

    // ---- phase 4: featurenet  K=224 (7 kt), relu -> sB (stride 132) ----
    {
        f32x4 acc[4][2];
#pragma unroll
        for (int mt = 0; mt < 4; mt++)
#pragma unroll
            for (int n2 = 0; n2 < 2; n2++) acc[mt][n2] = (f32x4){0.f, 0.f, 0.f, 0.f};
#pragma unroll
        for (int kt = 0; kt < 7; kt++) {
            bf16x8 a[4];
#pragma unroll
            for (int mt = 0; mt < 4; mt++)
                a[mt] = *(const bf16x8*)(sA + (mt * 16 + l15) * 232 + (kt * 4 + q) * 8);
#pragma unroll
            for (int n2 = 0; n2 < 2; n2++) {
                const bf16x8 b = *(const bf16x8*)(fnw + (((ntb + n2) * 7 + kt) * 64 + lane) * 8);
#pragma unroll
                for (int mt = 0; mt < 4; mt++) acc[mt][n2] = MFMA16(a[mt], b, acc[mt][n2]);
            }
        }
#pragma unroll
        for (int n2 = 0; n2 < 2; n2++) {
            const int n0 = (ntb + n2) * 16 + l15;
            const float bv = fn_b0[n0];
#pragma unroll
            for (int mt = 0; mt < 4; mt++)
#pragma unroll
                for (int rg = 0; rg < 4; rg++)
                    sB[(mt * 16 + q * 4 + rg) * 132 + n0] = bf16r(fmaxf(acc[mt][n2][rg] + bv, 0.f));
        }
    }
    __syncthreads();

    // ---- phase 5: dec_wf  K=128 (4 kt), no relu -> sA (stride 136) ----
    {
        f32x4 acc[4][2];
#pragma unroll
        for (int mt = 0; mt < 4; mt++)
#pragma unroll
            for (int n2 = 0; n2 < 2; n2++) acc[mt][n2] = (f32x4){0.f, 0.f, 0.f, 0.f};
#pragma unroll
        for (int kt = 0; kt < 4; kt++) {
            bf16x8 a[4];
#pragma unroll
            for (int mt = 0; mt < 4; mt++)
                a[mt] = *(const bf16x8*)(sB + (mt * 16 + l15) * 132 + (kt * 4 + q) * 8);
#pragma unroll
            for (int n2 = 0; n2 < 2; n2++) {
                const bf16x8 b = *(const bf16x8*)(dwf + (((ntb + n2) * 4 + kt) * 64 + lane) * 8);
#pragma unroll
                for (int mt = 0; mt < 4; mt++) acc[mt][n2] = MFMA16(a[mt], b, acc[mt][n2]);
            }
        }
#pragma unroll
        for (int n2 = 0; n2 < 2; n2++) {
            const int n0 = (ntb + n2) * 16 + l15;
            const float bv = dec_bf[n0];
#pragma unroll
            for (int mt = 0; mt < 4; mt++)
#pragma unroll
                for (int rg = 0; rg < 4; rg++)
                    sA[(mt * 16 + q * 4 + rg) * 136 + n0] = bf16r(acc[mt][n2][rg] + bv);
        }
    }
    __syncthreads();

    // ---- phase 6: dec_w0  K=128 (vemb folded in sBe3), N=64 (1 nt/wave);
    //      also stage dec_w1/dec_b1 into dead sB space [short 4608..] ----
    {
        float* sDw = (float*)sB + 2304;   // byte 9216, beyond h2dec (4608 shorts)
        for (int i = tid; i < 195; i += 256)
            sDw[i] = (i < 192) ? dec_w1[i] : dec_b1[i - 192];
        f32x4 acc[4];
#pragma unroll
        for (int mt = 0; mt < 4; mt++) acc[mt] = (f32x4){0.f, 0.f, 0.f, 0.f};
#pragma unroll
        for (int kt = 0; kt < 4; kt++) {
            bf16x8 a[4];
#pragma unroll
            for (int mt = 0; mt < 4; mt++)
                a[mt] = *(const bf16x8*)(sA + (mt * 16 + l15) * 136 + (kt * 4 + q) * 8);
            const bf16x8 b = *(const bf16x8*)(dw0 + ((wv * 4 + kt) * 64 + lane) * 8);
#pragma unroll
            for (int mt = 0; mt < 4; mt++) acc[mt] = MFMA16(a[mt], b, acc[mt]);
        }
        const int n0 = wv * 16 + l15;
        const float bv = sBe3[n0];
#pragma unroll
        for (int mt = 0; mt < 4; mt++)
#pragma unroll
            for (int rg = 0; rg < 4; rg++)
                sB[(mt * 16 + q * 4 + rg) * 72 + n0] = bf16r(fmaxf(acc[mt][rg] + bv, 0.f));
    }
    __syncthreads();

    // ---- phase 7: 64->3, sigmoid, weight, wave-reduce, store ----
    if (tid < 64) {
        const int p = tid;
        const float* sDw = (const float*)sB + 2304;
        float a0 = sDw[192], a1 = sDw[193], a2 = sDw[194];
#pragma unroll
        for (int g = 0; g < 8; g++) {
            const bf16x8 h = *(const bf16x8*)(sB + p * 72 + g * 8);
#pragma unroll
            for (int j = 0; j < 8; j++) {
                const float f = bf2f((unsigned short)h[j]);
                const int k = g * 8 + j;
                a0 += f * sDw[k * 3];
                a1 += f * sDw[k * 3 + 1];
                a2 += f * sDw[k * 3 + 2];
            }
        }
        const float wgt = sSm[p * 4 + 3];
        float r0 = wgt / (1.f + expf(-a0));
        float r1 = wgt / (1.f + expf(-a1));
        float r2 = wgt / (1.f + expf(-a2));
#pragma unroll
        for (int off = 32; off >= 1; off >>= 1) {
            r0 += __shfl_down(r0, off);
            r1 += __shfl_down(r1, off);
            r2 += __shfl_down(r2, off);
        }
        if (p == 0) {
            const float av = sAiv[0];
            out[r * 3]     = r0 + av;
            out[r * 3 + 1] = r1 + av;
            out[r * 3 + 2] = r2 + av;
        }
    }
}

// ---------------------------------------------------------------------------
extern "C" void kernel_launch(void* const* d_in, const int* in_sizes, int n_in,
                              void* d_out, int out_size, void* d_ws, size_t ws_size,
                              hipStream_t stream)
{
    const float* ray_pts    = (const float*)d_in[0];
    const float* viewdirs   = (const float*)d_in[1];
    const float* frame_time = (const float*)d_in[2];
    float*       feature    = (float*)d_in[3];          // clobbered only in small-ws path
    const float* density    = (const float*)d_in[4];
    const float* tn_w0 = (const float*)d_in[5];  const float* tn_b0 = (const float*)d_in[6];
    const float* tn_w1 = (const float*)d_in[7];  const float* tn_b1 = (const float*)d_in[8];
    const float* dt_w0 = (const float*)d_in[9];  const float* dt_b0 = (const float*)d_in[10];
    const float* dt_w1 = (const float*)d_in[11]; const float* dt_b1 = (const float*)d_in[12];
    const float* dt_wo = (const float*)d_in[13]; const float* dt_bo = (const float*)d_in[14];
    const float* fn_w0 = (const float*)d_in[15]; const float* fn_b0 = (const float*)d_in[16];
    const float* dec_wf = (const float*)d_in[17]; const float* dec_bf = (const float*)d_in[18];
    const float* dec_w0 = (const float*)d_in[19]; const float* dec_b0 = (const float*)d_in[20];
    const float* dec_w1 = (const float*)d_in[21]; const float* dec_b1 = (const float*)d_in[22];
    (void)in_sizes; (void)n_in; (void)out_size;

    char* ws = (char*)d_ws;
    const bool big = ws_size >= (size_t)57598464;

    short *G, *p2, *p4, *B1 = nullptr, *B2 = nullptr;
    float* be0; short *dt0h, *dt0l, *dt1h, *dt1l, *fnw, *dwf, *dw0;

    if (big) {
        G    = (short*)(ws + 0);            // 128^3*12 bf16 = 50331648 B
        p2   = (short*)(ws + 50331648);
        p4   = (short*)(ws + 56623104);
        be0  = (float*)(ws + 57409536);
        dt0h = (short*)(ws + 57410048);
        dt0l = (short*)(ws + 57418240);
        dt1h = (short*)(ws + 57426432);
        dt1l = (short*)(ws + 57459200);
        fnw  = (short*)(ws + 57491968);
        dwf  = (short*)(ws + 57549312);
        dw0  = (short*)(ws + 57582080);     // ends 57598464
    } else {
        G    = (short*)feature;             // in-place in feature buffer
        B1   = (short*)(ws + 0);            // 3*GV bf16
        B2   = (short*)(ws + 12582912);     // 3*GVH bf16
        p2   = (short*)(ws + 0);            // reuse after transpose
        p4   = (short*)(ws + 6291456);
        be0  = (float*)(ws + 18874368);
        dt0h = (short*)(ws + 18874880);
        dt0l = (short*)(ws + 18883072);
        dt1h = (short*)(ws + 18891264);
        dt1l = (short*)(ws + 18924032);
        fnw  = (short*)(ws + 18956800);
        dwf  = (short*)(ws + 19014144);
        dw0  = (short*)(ws + 19046912);     // ends 19063296
    }

    pack_timenet_kernel<<<289, 256, 0, stream>>>(
        dt_w0, dt_w1, fn_w0, dec_wf, dec_w0,
        frame_time, tn_w0, tn_b0, tn_w1, tn_b1, dt_b0,
        dt0h, dt0l, dt1h, dt1l, fnw, dwf, dw0, be0);

    if (big) {
        transpose_big_kernel<<<2048, 256, 0, stream>>>(feature, G);
    } else {
        compact_kernel<<<9216, 256, 0, stream>>>(feature, B1, B2);
        transpose_kernel<<<1024, 256, 0, stream>>>(feature, B1, B2, G, 0);
        transpose_kernel<<<1024, 256, 0, stream>>>(feature, B1, B2, G, 1);
    }
    pool_kernel<<<256, 256, 0, stream>>>(G, p2, 6);
    pool_kernel<<<32, 256, 0, stream>>>(p2, p4, 5);

    fused_kernel<<<4096, 256, 0, stream>>>(ray_pts, viewdirs, be0,
                                           dt0h, dt0l, dt1h, dt1l, dt_b1,
                                           dt_wo, dt_bo, density,
                                           G, p2, p4,
                                           fnw, fn_b0, dwf, dec_bf,
                                           dw0, dec_b0, dec_w0, dec_w1, dec_b1,
                                           (float*)d_out);
}